// Round 5
// baseline (787.496 us; speedup 1.0000x reference)
//
#include <hip/hip_runtime.h>
#include <hip/hip_cooperative_groups.h>

namespace cg = cooperative_groups;

#define N_NODES 50000
#define N_EDGES 800000
#define IN_C 128
#define MSG_C 64
#define OUT_C 128
#define SCAN_NB 49            // ceil(50000/1024)
#define NBLK 1024             // cooperative grid: 4 blocks/CU x 256 CU
#define GSTRIDE (NBLK * 256)

typedef __attribute__((ext_vector_type(8))) short short8v;  // 8 bf16 (4 VGPRs)
typedef __attribute__((ext_vector_type(4))) float f32x4;

__device__ __forceinline__ unsigned short f2bf(float f) {
    union { float f; unsigned int u; } v; v.f = f;
    unsigned int r = (v.u + 0x7FFFu + ((v.u >> 16) & 1u)) >> 16;
    return (unsigned short)r;
}

// ---------------------------------------------------------------------------
// ONE cooperative kernel: zero+convert -> hist -> scan -> fill -> gather
// 1024 blocks x 256 threads (4 blocks/CU co-resident, tiny LDS/VGPR)
// ---------------------------------------------------------------------------
__global__ __launch_bounds__(256, 4) void build_kernel(
    const int* __restrict__ edge_index, const float* __restrict__ message,
    int* __restrict__ degc,            // deg[N] ++ cursor[N], contiguous
    int* __restrict__ offsets,         // N+1
    int* __restrict__ elist,           // E
    unsigned short* __restrict__ aggr_bf,
    int* __restrict__ bsum,            // SCAN_NB
    const float* __restrict__ W1, const float* __restrict__ W2,
    const float* __restrict__ W3, unsigned short* __restrict__ Wt1,
    unsigned short* __restrict__ Wt2, unsigned short* __restrict__ Wt3)
{
    cg::grid_group grid = cg::this_grid();
    const int tid  = threadIdx.x;
    const int gtid = blockIdx.x * 256 + tid;
    const int lane = tid & 63, wid = tid >> 6;
    int* deg    = degc;
    int* cursor = degc + N_NODES;

    __shared__ int wtot[4];
    __shared__ int wexc[4];
    __shared__ int btot;
    __shared__ int bpre_s[SCAN_NB];
    __shared__ int gtot_s;

    // ---- P0: zero deg+cursor; transpose+convert weights to bf16 Wt[n][k]
    if (gtid < 2 * N_NODES) degc[gtid] = 0;
    if (gtid < 57344) {
        int idx = gtid;
        if (idx < 24576) {
            int k = idx >> 7, n = idx & 127;
            Wt1[n * 192 + k] = f2bf(W1[idx]);
        } else if (idx < 40960) {
            int t = idx - 24576;
            int k = t >> 7, n = t & 127;
            Wt2[n * 128 + k] = f2bf(W2[t]);
        } else {
            int t = idx - 40960;
            int k = t >> 7, n = t & 127;
            Wt3[n * 128 + k] = f2bf(W3[t]);
        }
    }
    grid.sync();

    // ---- P1: histogram of dest
    for (int e = gtid; e < N_EDGES; e += GSTRIDE)
        atomicAdd(&deg[edge_index[N_EDGES + e]], 1);
    grid.sync();

    // ---- P2: per-block scan of 1024-elt chunks (first SCAN_NB blocks)
    if (blockIdx.x < SCAN_NB) {
        int i0 = blockIdx.x * 1024 + tid * 4;
        int v[4];
        #pragma unroll
        for (int u = 0; u < 4; ++u) {
            int i = i0 + u;
            v[u] = (i < N_NODES) ? deg[i] : 0;
        }
        int tsum = v[0] + v[1] + v[2] + v[3];
        int s = tsum;
        #pragma unroll
        for (int d = 1; d < 64; d <<= 1) {
            int t = __shfl_up(s, d);
            if (lane >= d) s += t;
        }
        if (lane == 63) wtot[wid] = s;
        __syncthreads();
        if (tid == 0) {
            int a = 0;
            #pragma unroll
            for (int u = 0; u < 4; ++u) { wexc[u] = a; a += wtot[u]; }
            btot = a;
        }
        __syncthreads();
        int run = wexc[wid] + (s - tsum);
        #pragma unroll
        for (int u = 0; u < 4; ++u) {
            int i = i0 + u;
            if (i < N_NODES) offsets[i] = run;
            run += v[u];
        }
        if (tid == 0) bsum[blockIdx.x] = btot;
    }
    grid.sync();

    // ---- P3: every block redundantly scans bsum; add block prefix
    if (tid < 64) {
        int vv = (tid < SCAN_NB) ? bsum[tid] : 0;
        int ss = vv;
        #pragma unroll
        for (int d = 1; d < 64; d <<= 1) {
            int t = __shfl_up(ss, d);
            if (tid >= d) ss += t;
        }
        if (tid < SCAN_NB) bpre_s[tid] = ss - vv;
        if (tid == SCAN_NB - 1) gtot_s = ss;
    }
    __syncthreads();
    for (int i = gtid; i < N_NODES; i += GSTRIDE)
        offsets[i] += bpre_s[i >> 10];
    if (gtid == 0) offsets[N_NODES] = gtot_s;   // == N_EDGES
    grid.sync();

    // ---- P4: fill edge list
    for (int e = gtid; e < N_EDGES; e += GSTRIDE) {
        int d = edge_index[N_EDGES + e];
        int pos = atomicAdd(&cursor[d], 1);
        elist[offsets[d] + pos] = e;
    }
    grid.sync();

    // ---- P5: gather, one wave per node, 8 message rows in flight
    int gw = gtid >> 6;                 // 0..4095
    const int nw = GSTRIDE >> 6;        // 4096 waves
    for (int n = gw; n < N_NODES; n += nw) {
        int s0 = offsets[n], e0 = offsets[n + 1];
        float acc = 0.f;
        for (int i = s0; i < e0; i += 8) {
            int id[8];
            #pragma unroll
            for (int u = 0; u < 8; ++u) {
                int ii = i + u;
                id[u] = elist[ii < e0 ? ii : e0 - 1];   // clamp: valid addr
            }
            #pragma unroll
            for (int u = 0; u < 8; ++u) {
                float mv = message[(long)id[u] * MSG_C + lane];
                if (i + u < e0) acc += mv;
            }
        }
        aggr_bf[(long)n * MSG_C + lane] = f2bf(acc);
    }
}

// ---------------------------------------------------------------------------
// MFMA MLP + LayerNorm (unchanged from round 3/4). 4 waves x 16 rows, no syncs.
// ---------------------------------------------------------------------------
template<int KW, int AS, bool BIAS>
__device__ __forceinline__ void layer_mfma(const unsigned short* __restrict__ A,
                                           const unsigned short* __restrict__ Wt,
                                           const float* __restrict__ bias,
                                           int lr, int lg, f32x4 acc[8])
{
    #pragma unroll
    for (int ct = 0; ct < 8; ++ct) {
        float bv = BIAS ? bias[ct * 16 + lr] : 0.f;
        acc[ct] = (f32x4){bv, bv, bv, bv};
    }
    #pragma unroll
    for (int ks = 0; ks < KW / 32; ++ks) {
        short8v a = *reinterpret_cast<const short8v*>(A + lr * AS + ks * 32 + lg * 8);
        #pragma unroll
        for (int ct = 0; ct < 8; ++ct) {
            short8v b = *reinterpret_cast<const short8v*>(
                Wt + (size_t)(ct * 16 + lr) * KW + ks * 32 + lg * 8);
            acc[ct] = __builtin_amdgcn_mfma_f32_16x16x32_bf16(a, b, acc[ct], 0, 0, 0);
        }
    }
}

__device__ __forceinline__ void store_h_leaky(unsigned short* __restrict__ H,
                                              int lr, int lg, const f32x4 acc[8])
{
    #pragma unroll
    for (int ct = 0; ct < 8; ++ct)
        #pragma unroll
        for (int j = 0; j < 4; ++j) {
            float v = acc[ct][j];
            v = v > 0.f ? v : 0.2f * v;
            H[(lg * 4 + j) * 136 + ct * 16 + lr] = f2bf(v);
        }
}

__global__ __launch_bounds__(256, 2) void mlp_mfma_kernel(
    const float* __restrict__ x, const unsigned short* __restrict__ aggr_bf,
    const unsigned short* __restrict__ Wt1, const float* __restrict__ b1,
    const unsigned short* __restrict__ Wt2, const float* __restrict__ b2,
    const unsigned short* __restrict__ Wt3, const float* __restrict__ gamma,
    const float* __restrict__ beta, float* __restrict__ out)
{
    __shared__ __align__(16) unsigned short sA0[4][16][200];     // h0, stride 400B
    __shared__ __align__(16) unsigned short sH[4][2][16][136];   // h1,h2 stride 272B

    const int tid = threadIdx.x;
    const int w = tid >> 6, l = tid & 63;
    const int lr = l & 15, lg = l >> 4;
    const int R0 = blockIdx.x * 64 + w * 16;
    if (R0 >= N_NODES) return;    // N % 16 == 0: waves are all-or-nothing

    // ---- stage x (f32 -> bf16) into sA0[:, 0:128]
    #pragma unroll
    for (int i = 0; i < 4; ++i) {
        int r = lg + i * 4;
        int c0 = lr * 8;
        const float4* xp = reinterpret_cast<const float4*>(x + (size_t)(R0 + r) * IN_C + c0);
        float4 v0 = xp[0], v1 = xp[1];
        uint4 p;
        p.x = (unsigned)f2bf(v0.x) | ((unsigned)f2bf(v0.y) << 16);
        p.y = (unsigned)f2bf(v0.z) | ((unsigned)f2bf(v0.w) << 16);
        p.z = (unsigned)f2bf(v1.x) | ((unsigned)f2bf(v1.y) << 16);
        p.w = (unsigned)f2bf(v1.z) | ((unsigned)f2bf(v1.w) << 16);
        *reinterpret_cast<uint4*>(&sA0[w][r][c0]) = p;
    }
    // ---- stage aggr (already bf16) into sA0[:, 128:192]
    #pragma unroll
    for (int i = 0; i < 2; ++i) {
        int r = (l >> 3) + i * 8;
        int c0 = (l & 7) * 8;
        uint4 a4 = *reinterpret_cast<const uint4*>(aggr_bf + (size_t)(R0 + r) * MSG_C + c0);
        *reinterpret_cast<uint4*>(&sA0[w][r][IN_C + c0]) = a4;
    }

    f32x4 acc[8];

    // layer 1: K=192
    layer_mfma<192, 200, true>(&sA0[w][0][0], Wt1, b1, lr, lg, acc);
    store_h_leaky(&sH[w][0][0][0], lr, lg, acc);

    // layer 2: K=128
    layer_mfma<128, 136, true>(&sH[w][0][0][0], Wt2, b2, lr, lg, acc);
    store_h_leaky(&sH[w][1][0][0], lr, lg, acc);

    // layer 3: K=128, no bias
    layer_mfma<128, 136, false>(&sH[w][1][0][0], Wt3, nullptr, lr, lg, acc);

    // ---- LayerNorm epilogue
    float g8[8], be8[8];
    #pragma unroll
    for (int ct = 0; ct < 8; ++ct) {
        g8[ct] = gamma[ct * 16 + lr];
        be8[ct] = beta[ct * 16 + lr];
    }
    #pragma unroll
    for (int j = 0; j < 4; ++j) {
        float s1 = 0.f, s2 = 0.f;
        #pragma unroll
        for (int ct = 0; ct < 8; ++ct) {
            float v = acc[ct][j];
            s1 += v; s2 += v * v;
        }
        #pragma unroll
        for (int m = 8; m >= 1; m >>= 1) {
            s1 += __shfl_xor(s1, m);
            s2 += __shfl_xor(s2, m);
        }
        float mu = s1 * (1.f / 128.f);
        float var = s2 * (1.f / 128.f) - mu * mu;
        float rs = rsqrtf(var + 1e-5f);
        int gr = R0 + lg * 4 + j;
        #pragma unroll
        for (int ct = 0; ct < 8; ++ct)
            out[(size_t)gr * OUT_C + ct * 16 + lr] =
                (acc[ct][j] - mu) * rs * g8[ct] + be8[ct];
    }
}

extern "C" void kernel_launch(void* const* d_in, const int* in_sizes, int n_in,
                              void* d_out, int out_size, void* d_ws, size_t ws_size,
                              hipStream_t stream)
{
    const float* x       = (const float*)d_in[0];
    const int*   edge    = (const int*)d_in[1];
    const float* message = (const float*)d_in[2];
    const float* W1      = (const float*)d_in[3];
    const float* b1      = (const float*)d_in[4];
    const float* W2      = (const float*)d_in[5];
    const float* b2      = (const float*)d_in[6];
    const float* W3      = (const float*)d_in[7];
    const float* gamma   = (const float*)d_in[8];
    const float* beta    = (const float*)d_in[9];
    float* out  = (float*)d_out;

    // ---- workspace layout (~10.3 MB) ----
    char* ws = (char*)d_ws;
    unsigned short* aggr_bf = (unsigned short*)(ws);        //  6,400,000 B
    int*   degc    = (int*)(ws + 6400000);                  //    400,000 B (deg+cursor)
    int*   offsets = (int*)(ws + 6800000);                  //    200,016 B (N+1)
    int*   elist   = (int*)(ws + 7000016);                  //  3,200,000 B
    unsigned short* Wt1 = (unsigned short*)(ws + 10200016); //     49,152 B
    unsigned short* Wt2 = (unsigned short*)(ws + 10249168); //     32,768 B
    unsigned short* Wt3 = (unsigned short*)(ws + 10281936); //     32,768 B
    int*   bsum    = (int*)(ws + 10314704);                 //        196 B

    void* args[] = {
        (void*)&edge, (void*)&message, (void*)&degc, (void*)&offsets,
        (void*)&elist, (void*)&aggr_bf, (void*)&bsum,
        (void*)&W1, (void*)&W2, (void*)&W3,
        (void*)&Wt1, (void*)&Wt2, (void*)&Wt3
    };
    hipLaunchCooperativeKernel((const void*)build_kernel, dim3(NBLK), dim3(256),
                               args, 0, stream);

    mlp_mfma_kernel<<<(N_NODES + 63) / 64, 256, 0, stream>>>(
        x, aggr_bf, Wt1, b1, Wt2, b2, Wt3, gamma, beta, out);
}

// Round 6
// 201.483 us; speedup vs baseline: 3.9085x; 3.9085x over previous
//
#include <hip/hip_runtime.h>

#define N_NODES 50000
#define N_EDGES 800000
#define IN_C 128
#define MSG_C 64
#define OUT_C 128
#define SCAN_NB 49   // ceil(50000/1024)

typedef __attribute__((ext_vector_type(8))) short short8v;  // 8 bf16 (4 VGPRs)
typedef __attribute__((ext_vector_type(4))) float f32x4;

__device__ __forceinline__ unsigned short f2bf(float f) {
    union { float f; unsigned int u; } v; v.f = f;
    unsigned int r = (v.u + 0x7FFFu + ((v.u >> 16) & 1u)) >> 16;
    return (unsigned short)r;
}

// ---------------------------------------------------------------------------
// init: zero deg (12500 int4) + transpose/convert weights to bf16 Wt[n][k]
// ---------------------------------------------------------------------------
__global__ __launch_bounds__(256) void init_kernel(
    int4* __restrict__ deg4,
    const float* __restrict__ W1, const float* __restrict__ W2,
    const float* __restrict__ W3, unsigned short* __restrict__ Wt1,
    unsigned short* __restrict__ Wt2, unsigned short* __restrict__ Wt3)
{
    int idx = blockIdx.x * 256 + threadIdx.x;
    if (idx < 12500) deg4[idx] = make_int4(0, 0, 0, 0);
    if (idx < 24576) {
        int k = idx >> 7, n = idx & 127;
        Wt1[n * 192 + k] = f2bf(W1[idx]);
    } else if (idx < 40960) {
        int t = idx - 24576;
        int k = t >> 7, n = t & 127;
        Wt2[n * 128 + k] = f2bf(W2[t]);
    } else if (idx < 57344) {
        int t = idx - 40960;
        int k = t >> 7, n = t & 127;
        Wt3[n * 128 + k] = f2bf(W3[t]);
    }
}

// ---------------------------------------------------------------------------
// CSR build: histogram -> two-level scan -> fill edge list
// ---------------------------------------------------------------------------
__global__ __launch_bounds__(256) void hist_kernel(const int* __restrict__ edge_index,
                                                   int* __restrict__ deg)
{
    int i = blockIdx.x * 256 + threadIdx.x;
    if (i >= N_EDGES / 4) return;
    int4 d4 = *reinterpret_cast<const int4*>(edge_index + N_EDGES + i * 4);
    atomicAdd(&deg[d4.x], 1);
    atomicAdd(&deg[d4.y], 1);
    atomicAdd(&deg[d4.z], 1);
    atomicAdd(&deg[d4.w], 1);
}

__global__ __launch_bounds__(1024) void scan_a_kernel(const int* __restrict__ deg,
                                                      int* __restrict__ offsets,
                                                      int* __restrict__ bsum)
{
    __shared__ int wsum[16];
    const int tid = threadIdx.x, lane = tid & 63, wid = tid >> 6;
    int i = blockIdx.x * 1024 + tid;
    int v = (i < N_NODES) ? deg[i] : 0;
    int s = v;
    #pragma unroll
    for (int d = 1; d < 64; d <<= 1) {
        int t = __shfl_up(s, d);
        if (lane >= d) s += t;
    }
    if (lane == 63) wsum[wid] = s;
    __syncthreads();
    if (wid == 0 && lane < 16) {
        int ws = wsum[lane];
        int ss = ws;
        #pragma unroll
        for (int d = 1; d < 16; d <<= 1) {
            int t = __shfl_up(ss, d);
            if (lane >= d) ss += t;
        }
        wsum[lane] = ss - ws;   // exclusive wave offset
    }
    __syncthreads();
    if (i < N_NODES) offsets[i] = s - v + wsum[wid];
    if (tid == 1023) bsum[blockIdx.x] = wsum[15] + s;
}

__global__ __launch_bounds__(64) void scan_b_kernel(int* __restrict__ bsum,
                                                    int* __restrict__ offsets)
{
    int lane = threadIdx.x;
    int v = (lane < SCAN_NB) ? bsum[lane] : 0;
    int s = v;
    #pragma unroll
    for (int d = 1; d < 64; d <<= 1) {
        int t = __shfl_up(s, d);
        if (lane >= d) s += t;
    }
    if (lane < SCAN_NB) bsum[lane] = s - v;      // exclusive block offset
    if (lane == 63) offsets[N_NODES] = s;        // grand total == N_EDGES
}

// finalize offsets AND seed cursor with the same values
__global__ __launch_bounds__(256) void scan_c_kernel(int* __restrict__ offsets,
                                                     int* __restrict__ cursor,
                                                     const int* __restrict__ bsum)
{
    int i = blockIdx.x * 256 + threadIdx.x;
    if (i < N_NODES) {
        int o = offsets[i] + bsum[i >> 10];
        offsets[i] = o;
        cursor[i] = o;
    }
}

__global__ __launch_bounds__(256) void fill_kernel(const int* __restrict__ edge_index,
                                                   int* __restrict__ cursor,
                                                   int* __restrict__ elist)
{
    int i = blockIdx.x * 256 + threadIdx.x;
    if (i >= N_EDGES / 4) return;
    int4 d4 = *reinterpret_cast<const int4*>(edge_index + N_EDGES + i * 4);
    int e = i * 4;
    elist[atomicAdd(&cursor[d4.x], 1)] = e;
    elist[atomicAdd(&cursor[d4.y], 1)] = e + 1;
    elist[atomicAdd(&cursor[d4.z], 1)] = e + 2;
    elist[atomicAdd(&cursor[d4.w], 1)] = e + 3;
}

// ---------------------------------------------------------------------------
// gather: one wave per node, lane = channel; 8 rows in flight, exact tail.
// nontemporal message loads (205 MB streamed once — keep L2 for metadata).
// ---------------------------------------------------------------------------
__global__ __launch_bounds__(256) void gather_kernel(const int* __restrict__ offsets,
                                                     const int* __restrict__ elist,
                                                     const float* __restrict__ message,
                                                     unsigned short* __restrict__ aggr_bf)
{
    int wid = threadIdx.x >> 6;
    int lane = threadIdx.x & 63;
    int n = blockIdx.x * 4 + wid;
    if (n >= N_NODES) return;
    int s0 = offsets[n], e0 = offsets[n + 1];
    float acc = 0.f;
    int i = s0;
    for (; i + 8 <= e0; i += 8) {
        int id[8];
        #pragma unroll
        for (int u = 0; u < 8; ++u) id[u] = elist[i + u];
        #pragma unroll
        for (int u = 0; u < 8; ++u)
            acc += __builtin_nontemporal_load(message + (long)id[u] * MSG_C + lane);
    }
    int rem = e0 - i;
    if (rem & 4) {
        int id[4];
        #pragma unroll
        for (int u = 0; u < 4; ++u) id[u] = elist[i + u];
        #pragma unroll
        for (int u = 0; u < 4; ++u)
            acc += __builtin_nontemporal_load(message + (long)id[u] * MSG_C + lane);
        i += 4;
    }
    if (rem & 2) {
        int id0 = elist[i], id1 = elist[i + 1];
        acc += __builtin_nontemporal_load(message + (long)id0 * MSG_C + lane);
        acc += __builtin_nontemporal_load(message + (long)id1 * MSG_C + lane);
        i += 2;
    }
    if (rem & 1)
        acc += __builtin_nontemporal_load(message + (long)elist[i] * MSG_C + lane);
    aggr_bf[(long)n * MSG_C + lane] = f2bf(acc);
}

// ---------------------------------------------------------------------------
// MFMA MLP + LayerNorm. 4 waves x 16 rows, wave-private LDS, no syncs.
// A-frag: row = lane&15, k = (lane>>4)*8 + j ; C/D: col = lane&15,
// row = (lane>>4)*4 + j  [m89-verified]
// ---------------------------------------------------------------------------
template<int KW, int AS, bool BIAS>
__device__ __forceinline__ void layer_mfma(const unsigned short* __restrict__ A,
                                           const unsigned short* __restrict__ Wt,
                                           const float* __restrict__ bias,
                                           int lr, int lg, f32x4 acc[8])
{
    #pragma unroll
    for (int ct = 0; ct < 8; ++ct) {
        float bv = BIAS ? bias[ct * 16 + lr] : 0.f;
        acc[ct] = (f32x4){bv, bv, bv, bv};
    }
    #pragma unroll
    for (int ks = 0; ks < KW / 32; ++ks) {
        short8v a = *reinterpret_cast<const short8v*>(A + lr * AS + ks * 32 + lg * 8);
        #pragma unroll
        for (int ct = 0; ct < 8; ++ct) {
            short8v b = *reinterpret_cast<const short8v*>(
                Wt + (size_t)(ct * 16 + lr) * KW + ks * 32 + lg * 8);
            acc[ct] = __builtin_amdgcn_mfma_f32_16x16x32_bf16(a, b, acc[ct], 0, 0, 0);
        }
    }
}

__device__ __forceinline__ void store_h_leaky(unsigned short* __restrict__ H,
                                              int lr, int lg, const f32x4 acc[8])
{
    #pragma unroll
    for (int ct = 0; ct < 8; ++ct)
        #pragma unroll
        for (int j = 0; j < 4; ++j) {
            float v = acc[ct][j];
            v = v > 0.f ? v : 0.2f * v;
            H[(lg * 4 + j) * 136 + ct * 16 + lr] = f2bf(v);
        }
}

__global__ __launch_bounds__(256, 2) void mlp_mfma_kernel(
    const float* __restrict__ x, const unsigned short* __restrict__ aggr_bf,
    const unsigned short* __restrict__ Wt1, const float* __restrict__ b1,
    const unsigned short* __restrict__ Wt2, const float* __restrict__ b2,
    const unsigned short* __restrict__ Wt3, const float* __restrict__ gamma,
    const float* __restrict__ beta, float* __restrict__ out)
{
    __shared__ __align__(16) unsigned short sA0[4][16][200];     // h0, stride 400B
    __shared__ __align__(16) unsigned short sH[4][2][16][136];   // h1,h2 stride 272B

    const int tid = threadIdx.x;
    const int w = tid >> 6, l = tid & 63;
    const int lr = l & 15, lg = l >> 4;
    const int R0 = blockIdx.x * 64 + w * 16;
    if (R0 >= N_NODES) return;    // N % 16 == 0: waves are all-or-nothing

    // ---- stage x (f32 -> bf16) into sA0[:, 0:128]
    #pragma unroll
    for (int i = 0; i < 4; ++i) {
        int r = lg + i * 4;
        int c0 = lr * 8;
        const float4* xp = reinterpret_cast<const float4*>(x + (size_t)(R0 + r) * IN_C + c0);
        float4 v0 = xp[0], v1 = xp[1];
        uint4 p;
        p.x = (unsigned)f2bf(v0.x) | ((unsigned)f2bf(v0.y) << 16);
        p.y = (unsigned)f2bf(v0.z) | ((unsigned)f2bf(v0.w) << 16);
        p.z = (unsigned)f2bf(v1.x) | ((unsigned)f2bf(v1.y) << 16);
        p.w = (unsigned)f2bf(v1.z) | ((unsigned)f2bf(v1.w) << 16);
        *reinterpret_cast<uint4*>(&sA0[w][r][c0]) = p;
    }
    // ---- stage aggr (already bf16) into sA0[:, 128:192]
    #pragma unroll
    for (int i = 0; i < 2; ++i) {
        int r = (l >> 3) + i * 8;
        int c0 = (l & 7) * 8;
        uint4 a4 = *reinterpret_cast<const uint4*>(aggr_bf + (size_t)(R0 + r) * MSG_C + c0);
        *reinterpret_cast<uint4*>(&sA0[w][r][IN_C + c0]) = a4;
    }

    f32x4 acc[8];

    // layer 1: K=192
    layer_mfma<192, 200, true>(&sA0[w][0][0], Wt1, b1, lr, lg, acc);
    store_h_leaky(&sH[w][0][0][0], lr, lg, acc);

    // layer 2: K=128
    layer_mfma<128, 136, true>(&sH[w][0][0][0], Wt2, b2, lr, lg, acc);
    store_h_leaky(&sH[w][1][0][0], lr, lg, acc);

    // layer 3: K=128, no bias
    layer_mfma<128, 136, false>(&sH[w][1][0][0], Wt3, nullptr, lr, lg, acc);

    // ---- LayerNorm epilogue
    float g8[8], be8[8];
    #pragma unroll
    for (int ct = 0; ct < 8; ++ct) {
        g8[ct] = gamma[ct * 16 + lr];
        be8[ct] = beta[ct * 16 + lr];
    }
    #pragma unroll
    for (int j = 0; j < 4; ++j) {
        float s1 = 0.f, s2 = 0.f;
        #pragma unroll
        for (int ct = 0; ct < 8; ++ct) {
            float v = acc[ct][j];
            s1 += v; s2 += v * v;
        }
        #pragma unroll
        for (int m = 8; m >= 1; m >>= 1) {
            s1 += __shfl_xor(s1, m);
            s2 += __shfl_xor(s2, m);
        }
        float mu = s1 * (1.f / 128.f);
        float var = s2 * (1.f / 128.f) - mu * mu;
        float rs = rsqrtf(var + 1e-5f);
        int gr = R0 + lg * 4 + j;
        #pragma unroll
        for (int ct = 0; ct < 8; ++ct)
            out[(size_t)gr * OUT_C + ct * 16 + lr] =
                (acc[ct][j] - mu) * rs * g8[ct] + be8[ct];
    }
}

extern "C" void kernel_launch(void* const* d_in, const int* in_sizes, int n_in,
                              void* d_out, int out_size, void* d_ws, size_t ws_size,
                              hipStream_t stream)
{
    const float* x       = (const float*)d_in[0];
    const int*   edge    = (const int*)d_in[1];
    const float* message = (const float*)d_in[2];
    const float* W1      = (const float*)d_in[3];
    const float* b1      = (const float*)d_in[4];
    const float* W2      = (const float*)d_in[5];
    const float* b2      = (const float*)d_in[6];
    const float* W3      = (const float*)d_in[7];
    const float* gamma   = (const float*)d_in[8];
    const float* beta    = (const float*)d_in[9];
    float* out  = (float*)d_out;

    // ---- workspace layout (~10.3 MB) ----
    char* ws = (char*)d_ws;
    unsigned short* aggr_bf = (unsigned short*)(ws);        //  6,400,000 B
    int*   deg     = (int*)(ws + 6400000);                  //    200,000 B
    int*   cursor  = (int*)(ws + 6600000);                  //    200,000 B
    int*   offsets = (int*)(ws + 6800000);                  //    200,016 B (N+1)
    int*   elist   = (int*)(ws + 7000016);                  //  3,200,000 B
    unsigned short* Wt1 = (unsigned short*)(ws + 10200016); //     49,152 B
    unsigned short* Wt2 = (unsigned short*)(ws + 10249168); //     32,768 B
    unsigned short* Wt3 = (unsigned short*)(ws + 10281936); //     32,768 B
    int*   bsum    = (int*)(ws + 10314704);                 //        196 B

    init_kernel<<<224, 256, 0, stream>>>((int4*)deg, W1, W2, W3, Wt1, Wt2, Wt3);

    int qblocks = (N_EDGES / 4 + 255) / 256;   // 782
    hist_kernel<<<qblocks, 256, 0, stream>>>(edge, deg);
    scan_a_kernel<<<SCAN_NB, 1024, 0, stream>>>(deg, offsets, bsum);
    scan_b_kernel<<<1, 64, 0, stream>>>(bsum, offsets);
    scan_c_kernel<<<(N_NODES + 255) / 256, 256, 0, stream>>>(offsets, cursor, bsum);
    fill_kernel<<<qblocks, 256, 0, stream>>>(edge, cursor, elist);

    gather_kernel<<<(N_NODES + 3) / 4, 256, 0, stream>>>(offsets, elist, message, aggr_bf);

    mlp_mfma_kernel<<<(N_NODES + 63) / 64, 256, 0, stream>>>(
        x, aggr_bf, Wt1, b1, Wt2, b2, Wt3, gamma, beta, out);
}